// Round 8
// baseline (1408.436 us; speedup 1.0000x reference)
//
#include <hip/hip_runtime.h>

#define U_N 100000
#define I_N 50000
#define D_N 64
#define B_N 4
#define E_N 2000000

#define EDGES   (B_N * E_N)            // 8,000,000 edge-entries per side
#define NSC_U   (U_N / 8)              // 12,500 chunks (8 rows x 4 behaviors)
#define NSC_I   (I_N / 8)              // 6,250 item chunks
#define CROW    12544                  // padded chunk-row length (>= NSC_U)
#define NBLK    256                    // partition blocks (32 per XCD)
#define EPB     (EDGES / NBLK)         // 31,250 entries per block (exact)
#define CAP     1536                   // fused-kernel LDS sort capacity (35 sigma)
#define XSTR    36                     // xs leading stride (dwords), pad vs 32
#define SC_T    13                     // 1024*13 >= 12,500

// Bin key: bin = row*4 + behavior -> chunk = row>>3, local = ((row&7)<<2)|b.
// User side: keys=rows, gathers item table. Item side: keys=cols, gathers user.

// ---------------------------------------------------------------------------
// Pass 0: convert both embedding tables to bf16 (RNE).
// ---------------------------------------------------------------------------
__global__ __launch_bounds__(256) void cvt_kernel(const float* __restrict__ ue,
                                                  const float* __restrict__ ie,
                                                  unsigned short* __restrict__ u16,
                                                  unsigned short* __restrict__ i16) {
    int i = blockIdx.x * 256 + threadIdx.x;
    int nu = U_N * D_N;
    int ni = I_N * D_N;
    if (i < nu) {
        unsigned u = __float_as_uint(ue[i]);
        u += 0x7FFFu + ((u >> 16) & 1u);
        u16[i] = (unsigned short)(u >> 16);
    } else if (i < nu + ni) {
        int j = i - nu;
        unsigned u = __float_as_uint(ie[j]);
        u += 0x7FFFu + ((u >> 16) & 1u);
        i16[j] = (unsigned short)(u >> 16);
    }
}

// ---------------------------------------------------------------------------
// Pass 1: per-(block, chunk) histogram; block lb owns entries [lb*EPB, ...).
// ---------------------------------------------------------------------------
__global__ __launch_bounds__(512) void bhist_kernel(const int* __restrict__ keys,
                                                    int nsc,
                                                    int* __restrict__ cnt) {
    __shared__ int h[CROW];
    for (int i = threadIdx.x; i < nsc; i += 512) h[i] = 0;
    __syncthreads();
    int lb = ((blockIdx.x & 7) << 5) | (blockIdx.x >> 3);
    int base = lb * EPB;
    for (int i = threadIdx.x; i < EPB; i += 512)
        atomicAdd(&h[keys[base + i] >> 3], 1);
    __syncthreads();
    int* row = cnt + (size_t)lb * CROW;
    for (int i = threadIdx.x; i < nsc; i += 512) row[i] = h[i];
}

// ---------------------------------------------------------------------------
// Pass 2: totals, exclusive scan, then counts -> per-block cursors in place.
// ---------------------------------------------------------------------------
__global__ __launch_bounds__(512) void scan_tot(const int* __restrict__ cnt,
                                                int nsc, int* __restrict__ cnt_ch) {
    int c = blockIdx.x * 512 + threadIdx.x;
    if (c >= nsc) return;
    int s = 0;
    for (int lb = 0; lb < NBLK; ++lb) s += cnt[(size_t)lb * CROW + c];
    cnt_ch[c] = s;
}

__global__ __launch_bounds__(1024) void scan_ex(const int* __restrict__ cnt_ch,
                                                int nsc, int* __restrict__ off_ch) {
    int t = threadIdx.x;
    int loc[SC_T]; int s = 0;
#pragma unroll
    for (int j = 0; j < SC_T; ++j) {
        int idx = t * SC_T + j;
        int c = (idx < nsc) ? cnt_ch[idx] : 0;
        loc[j] = s; s += c;
    }
    __shared__ int sm[1024];
    int mine = s; sm[t] = s; __syncthreads();
    for (int o = 1; o < 1024; o <<= 1) {
        int a = (t >= o) ? sm[t - o] : 0;
        __syncthreads(); sm[t] += a; __syncthreads();
    }
    int pre = sm[t] - mine;
#pragma unroll
    for (int j = 0; j < SC_T; ++j) {
        int idx = t * SC_T + j;
        if (idx < nsc) off_ch[idx] = pre + loc[j];
    }
}

__global__ __launch_bounds__(512) void scan_cur(int* __restrict__ cnt,
                                                const int* __restrict__ off_ch,
                                                int nsc) {
    int c = blockIdx.x * 512 + threadIdx.x;
    if (c >= nsc) return;
    int run = off_ch[c];
    for (int lb = 0; lb < NBLK; ++lb) {
        int v = cnt[(size_t)lb * CROW + c];
        cnt[(size_t)lb * CROW + c] = run;
        run += v;
    }
}

// ---------------------------------------------------------------------------
// Pass 3: placement, zero global atomics (LDS cursor row per block).
// pay = { local(5b)<<17 | src(17b), v (f32) }.
// ---------------------------------------------------------------------------
__global__ __launch_bounds__(512) void cplace_kernel(const int* __restrict__ keys,
                                                     const int* __restrict__ srcs,
                                                     const float* __restrict__ vals,
                                                     const int* __restrict__ cur_g,
                                                     int nsc,
                                                     uint2* __restrict__ pay) {
    __shared__ int cur[CROW];
    int lb = ((blockIdx.x & 7) << 5) | (blockIdx.x >> 3);
    const int* row = cur_g + (size_t)lb * CROW;
    for (int i = threadIdx.x; i < nsc; i += 512) cur[i] = row[i];
    __syncthreads();
    int base = lb * EPB;
    int b = lb >> 6;                     // behavior: 64 blocks per behavior
    for (int i = threadIdx.x; i < EPB; i += 512) {
        int gi = base + i;
        int k = keys[gi];
        float v = vals[gi];
        int src = srcs[gi];
        int pos = atomicAdd(&cur[k >> 3], 1);
        pay[pos] = make_uint2(((unsigned)(((k & 7) << 2) | b) << 17) | (unsigned)src,
                              __float_as_uint(v));
    }
}

// ---------------------------------------------------------------------------
// Pass 4 (fused): LDS counting-sort -> register accumulate (scalarized
// wave-uniform payload, saddr gathers) -> d-major xs -> transform + sigmoid
// + wave-local behavior mean. LDS ~25 KB -> 4 blocks/CU (100% occupancy).
// ---------------------------------------------------------------------------
__global__ __launch_bounds__(512) void fused_kernel(
        const unsigned short* __restrict__ emb16,
        const float* __restrict__ W,
        const int* __restrict__ off_ch,
        const int* __restrict__ cnt_ch,
        const uint2* __restrict__ pay,
        float* __restrict__ embs,        // [B][nrows][64] <- sigmoid(x@W)
        float* __restrict__ mean_out,    // [nrows][64]    <- sigmoid(mean@W)
        int nrows) {
    int g = blockIdx.x;
    int start = off_ch[g], n = cnt_ch[g];
    int t = threadIdx.x, w = t >> 6, lane = t & 63;

    __shared__ uint2 st[CAP];            // staging; reused as xs after sort
    __shared__ uint2 st2[CAP];           // sorted payload
    __shared__ int c32[32];
    __shared__ int bstart[33];
    float* xs = (float*)st;              // [64][XSTR] d-major accumulators

    if (n <= CAP) {
        if (t < 32) c32[t] = 0;
        __syncthreads();
        for (int i = t; i < n; i += 512) {
            uint2 p = pay[start + i];
            st[i] = p;
            atomicAdd(&c32[p.x >> 17], 1);
        }
        __syncthreads();
        if (t == 0) {
            int s = 0;
            for (int b2 = 0; b2 < 32; ++b2) {
                bstart[b2] = s; s += c32[b2]; c32[b2] = bstart[b2];
            }
            bstart[32] = s;
        }
        __syncthreads();
        for (int i = t; i < n; i += 512) {
            uint2 p = st[i];
            int pos = atomicAdd(&c32[p.x >> 17], 1);
            st2[pos] = p;
        }
        __syncthreads();
        // Register accumulation. Payload entries are wave-uniform ->
        // readfirstlane scalarizes value + gather base (saddr load form).
        float acc[4];
#pragma unroll
        for (int q = 0; q < 4; ++q) {
            int s0 = bstart[w * 4 + q], s1 = bstart[w * 4 + q + 1];
            float a = 0.f;
#pragma unroll 4
            for (int j = s0; j < s1; ++j) {
                uint2 pv = st2[j];
                unsigned pk = (unsigned)__builtin_amdgcn_readfirstlane((int)pv.x);
                float v = __uint_as_float(
                    (unsigned)__builtin_amdgcn_readfirstlane((int)pv.y));
                const unsigned short* rowp = emb16 + (size_t)(pk & 0x1FFFFu) * 64;
                float x = __uint_as_float((unsigned)rowp[lane] << 16);
                a = fmaf(v, x, a);
            }
            acc[q] = a;
        }
        // st is dead (sort copied to st2); alias as xs. Intra-wave dep only:
        // wave w writes xs[d=lane][w*4..] and reads the same slots below.
        *(float4*)&xs[lane * XSTR + w * 4] =
            make_float4(acc[0], acc[1], acc[2], acc[3]);
    } else {
        // fallback (never for this input): unsorted LDS-atomic accumulate
        for (int i = t; i < 64 * XSTR; i += 512) xs[i] = 0.f;
        __syncthreads();
        for (int j = w; j < n; j += 8) {
            uint2 pv = pay[start + j];
            unsigned pk = (unsigned)__builtin_amdgcn_readfirstlane((int)pv.x);
            float v = __uint_as_float(
                (unsigned)__builtin_amdgcn_readfirstlane((int)pv.y));
            float x = __uint_as_float(
                (unsigned)emb16[(size_t)(pk & 0x1FFFFu) * 64 + lane] << 16);
            atomicAdd(&xs[lane * XSTR + (int)(pk >> 17)], v * x);
        }
        __syncthreads();                 // cross-wave xs
    }

    // Transform: y[q][lane] = sum_d xs[d][w*4+q] * W[d][lane].
    // One broadcast ds_read_b128 per d serves all 4 bins.
    float y[4] = {0.f, 0.f, 0.f, 0.f};
#pragma unroll 4
    for (int d = 0; d < 64; ++d) {
        float4 xq = *(const float4*)&xs[d * XSTR + w * 4];
        float wv = W[d * 64 + lane];
        y[0] = fmaf(xq.x, wv, y[0]);
        y[1] = fmaf(xq.y, wv, y[1]);
        y[2] = fmaf(xq.z, wv, y[2]);
        y[3] = fmaf(xq.w, wv, y[3]);
    }
    int row = g * 8 + w;
#pragma unroll
    for (int q = 0; q < 4; ++q)
        embs[((long long)q * nrows + row) * 64 + lane] =
            1.f / (1.f + __expf(-y[q]));
    float m = 0.25f * (y[0] + y[1] + y[2] + y[3]);
    mean_out[(long long)row * 64 + lane] = 1.f / (1.f + __expf(-m));
}

// ---------------------------------------------------------------------------
// Deep fallback: atomic scatter + separate transform (only if ws too small).
// ---------------------------------------------------------------------------
__global__ void scatter_atomic_kernel(const float* __restrict__ user_emb,
                                      const float* __restrict__ item_emb,
                                      const int* __restrict__ rows,
                                      const int* __restrict__ cols,
                                      const float* __restrict__ vals,
                                      float* __restrict__ stack_u,
                                      float* __restrict__ stack_i) {
    long long tid = (long long)blockIdx.x * blockDim.x + threadIdx.x;
    long long e  = tid >> 4;
    int lane = (int)(tid & 15);
    if (e >= (long long)EDGES) return;
    int b = (int)(e / E_N);
    int r = rows[e];
    int c = cols[e];
    float v = vals[e];
    const float4* irow = (const float4*)(item_emb + (long long)c * D_N);
    const float4* urow = (const float4*)(user_emb + (long long)r * D_N);
    float4 iv = irow[lane];
    float4 uv = urow[lane];
    float* du = stack_u + ((long long)b * U_N + r) * D_N + lane * 4;
    float* di = stack_i + ((long long)b * I_N + c) * D_N + lane * 4;
    atomicAdd(du + 0, v * iv.x);
    atomicAdd(du + 1, v * iv.y);
    atomicAdd(du + 2, v * iv.z);
    atomicAdd(du + 3, v * iv.w);
    atomicAdd(di + 0, v * uv.x);
    atomicAdd(di + 1, v * uv.y);
    atomicAdd(di + 2, v * uv.z);
    atomicAdd(di + 3, v * uv.w);
}

template <int NROWS>
__global__ __launch_bounds__(64) void transform_kernel(
        float* __restrict__ stack,
        const float* __restrict__ W,
        float* __restrict__ mean_out) {
    const int row = blockIdx.x;
    const int j   = threadIdx.x;
    __shared__ float xs[B_N][D_N];
#pragma unroll
    for (int b = 0; b < B_N; ++b)
        xs[b][j] = stack[((long long)b * NROWS + row) * D_N + j];
    __syncthreads();
    float acc[B_N] = {0.f, 0.f, 0.f, 0.f};
#pragma unroll 8
    for (int d = 0; d < D_N; ++d) {
        float w = W[d * D_N + j];
#pragma unroll
        for (int b = 0; b < B_N; ++b)
            acc[b] += xs[b][d] * w;
    }
    float m = 0.25f * (acc[0] + acc[1] + acc[2] + acc[3]);
#pragma unroll
    for (int b = 0; b < B_N; ++b)
        stack[((long long)b * NROWS + row) * D_N + j] =
            1.0f / (1.0f + __expf(-acc[b]));
    mean_out[(long long)row * D_N + j] = 1.0f / (1.0f + __expf(-m));
}

// ---------------------------------------------------------------------------
extern "C" void kernel_launch(void* const* d_in, const int* in_sizes, int n_in,
                              void* d_out, int out_size, void* d_ws, size_t ws_size,
                              hipStream_t stream) {
    const float* user_emb = (const float*)d_in[0];
    const float* item_emb = (const float*)d_in[1];
    const int*   rows     = (const int*)  d_in[2];
    const int*   cols     = (const int*)  d_in[3];
    const float* vals     = (const float*)d_in[4];
    const float* u_w      = (const float*)d_in[5];
    const float* i_w      = (const float*)d_in[6];

    float* out = (float*)d_out;
    float* user_mean = out;
    float* item_mean = out + (long long)U_N * D_N;
    float* stack_u   = item_mean + (long long)I_N * D_N;     // user_embs out
    float* stack_i   = stack_u + (long long)B_N * U_N * D_N; // item_embs out

    // Workspace: cnt [NBLK][CROW] | cnt_ch | off_ch | pay [EDGES] | bf16 tables
    int* cnt    = (int*)d_ws;
    int* cnt_ch = cnt + (size_t)NBLK * CROW;
    int* off_ch = cnt_ch + CROW;
    uint2* pay  = (uint2*)(off_ch + CROW);
    unsigned short* user16 = (unsigned short*)(pay + EDGES);
    unsigned short* item16 = user16 + (size_t)U_N * D_N;
    size_t needed = ((size_t)NBLK * CROW + 2 * CROW) * 4 +
                    (size_t)EDGES * 8 + (size_t)(U_N + I_N) * D_N * 2; // ~96 MB

    if (ws_size >= needed) {
        int ncvt = (U_N + I_N) * D_N;
        cvt_kernel<<<(ncvt + 255) / 256, 256, 0, stream>>>(user_emb, item_emb,
                                                           user16, item16);
        // ---- user side: keys=rows, gathers item table ----
        bhist_kernel<<<NBLK, 512, 0, stream>>>(rows, NSC_U, cnt);
        scan_tot<<<(NSC_U + 511) / 512, 512, 0, stream>>>(cnt, NSC_U, cnt_ch);
        scan_ex<<<1, 1024, 0, stream>>>(cnt_ch, NSC_U, off_ch);
        scan_cur<<<(NSC_U + 511) / 512, 512, 0, stream>>>(cnt, off_ch, NSC_U);
        cplace_kernel<<<NBLK, 512, 0, stream>>>(rows, cols, vals, cnt, NSC_U, pay);
        fused_kernel<<<NSC_U, 512, 0, stream>>>(item16, u_w, off_ch, cnt_ch, pay,
                                                stack_u, user_mean, U_N);
        // ---- item side: keys=cols, gathers user table ----
        bhist_kernel<<<NBLK, 512, 0, stream>>>(cols, NSC_I, cnt);
        scan_tot<<<(NSC_I + 511) / 512, 512, 0, stream>>>(cnt, NSC_I, cnt_ch);
        scan_ex<<<1, 1024, 0, stream>>>(cnt_ch, NSC_I, off_ch);
        scan_cur<<<(NSC_I + 511) / 512, 512, 0, stream>>>(cnt, off_ch, NSC_I);
        cplace_kernel<<<NBLK, 512, 0, stream>>>(cols, rows, vals, cnt, NSC_I, pay);
        fused_kernel<<<NSC_I, 512, 0, stream>>>(user16, i_w, off_ch, cnt_ch, pay,
                                                stack_i, item_mean, I_N);
    } else {
        size_t stack_bytes = sizeof(float) * (size_t)B_N * (U_N + I_N) * D_N;
        hipMemsetAsync(stack_u, 0, stack_bytes, stream);
        long long nthreads = (long long)EDGES * 16;
        int nblocks = (int)((nthreads + 255) / 256);
        scatter_atomic_kernel<<<nblocks, 256, 0, stream>>>(
            user_emb, item_emb, rows, cols, vals, stack_u, stack_i);
        transform_kernel<U_N><<<U_N, 64, 0, stream>>>(stack_u, u_w, user_mean);
        transform_kernel<I_N><<<I_N, 64, 0, stream>>>(stack_i, i_w, item_mean);
    }
}

// Round 9
// 935.254 us; speedup vs baseline: 1.5059x; 1.5059x over previous
//
#include <hip/hip_runtime.h>

#define U_N 100000
#define I_N 50000
#define D_N 64
#define B_N 4
#define E_N 2000000

#define EDGES   (B_N * E_N)            // 8,000,000 edge-entries per side
#define NSC_U   (U_N / 8)              // 12,500 chunks (8 rows x 4 behaviors)
#define NSC_I   (I_N / 8)              // 6,250 item chunks
#define CROW    12544                  // padded chunk-row length (>= NSC_U)
#define NBLK    256                    // partition blocks (32 per XCD)
#define EPB     (EDGES / NBLK)         // 31,250 entries per block (exact)
#define CAP     1536                   // fused-kernel LDS sort capacity
#define XSTR    36                     // xs leading stride (dwords), pad vs 32
#define SC_T    13                     // 1024*13 >= 12,500

// Bin key: bin = row*4 + behavior -> chunk = row>>3, local = ((row&7)<<2)|b.
// User side: keys=rows, gathers item table. Item side: keys=cols, gathers user.

__device__ __forceinline__ float bf16x(const unsigned short* __restrict__ p) {
    return __uint_as_float((unsigned)(*p) << 16);
}

// ---------------------------------------------------------------------------
// Pass 0: convert both embedding tables to bf16 (RNE).
// ---------------------------------------------------------------------------
__global__ __launch_bounds__(256) void cvt_kernel(const float* __restrict__ ue,
                                                  const float* __restrict__ ie,
                                                  unsigned short* __restrict__ u16,
                                                  unsigned short* __restrict__ i16) {
    int i = blockIdx.x * 256 + threadIdx.x;
    int nu = U_N * D_N;
    int ni = I_N * D_N;
    if (i < nu) {
        unsigned u = __float_as_uint(ue[i]);
        u += 0x7FFFu + ((u >> 16) & 1u);
        u16[i] = (unsigned short)(u >> 16);
    } else if (i < nu + ni) {
        int j = i - nu;
        unsigned u = __float_as_uint(ie[j]);
        u += 0x7FFFu + ((u >> 16) & 1u);
        i16[j] = (unsigned short)(u >> 16);
    }
}

// ---------------------------------------------------------------------------
// Pass 1: per-(block, chunk) histogram; block lb owns entries [lb*EPB, ...).
// ---------------------------------------------------------------------------
__global__ __launch_bounds__(512) void bhist_kernel(const int* __restrict__ keys,
                                                    int nsc,
                                                    int* __restrict__ cnt) {
    __shared__ int h[CROW];
    for (int i = threadIdx.x; i < nsc; i += 512) h[i] = 0;
    __syncthreads();
    int lb = ((blockIdx.x & 7) << 5) | (blockIdx.x >> 3);
    int base = lb * EPB;
    for (int i = threadIdx.x; i < EPB; i += 512)
        atomicAdd(&h[keys[base + i] >> 3], 1);
    __syncthreads();
    int* row = cnt + (size_t)lb * CROW;
    for (int i = threadIdx.x; i < nsc; i += 512) row[i] = h[i];
}

// ---------------------------------------------------------------------------
// Pass 2: totals, exclusive scan, then counts -> per-block cursors in place.
// ---------------------------------------------------------------------------
__global__ __launch_bounds__(512) void scan_tot(const int* __restrict__ cnt,
                                                int nsc, int* __restrict__ cnt_ch) {
    int c = blockIdx.x * 512 + threadIdx.x;
    if (c >= nsc) return;
    int s = 0;
    for (int lb = 0; lb < NBLK; ++lb) s += cnt[(size_t)lb * CROW + c];
    cnt_ch[c] = s;
}

__global__ __launch_bounds__(1024) void scan_ex(const int* __restrict__ cnt_ch,
                                                int nsc, int* __restrict__ off_ch) {
    int t = threadIdx.x;
    int loc[SC_T]; int s = 0;
#pragma unroll
    for (int j = 0; j < SC_T; ++j) {
        int idx = t * SC_T + j;
        int c = (idx < nsc) ? cnt_ch[idx] : 0;
        loc[j] = s; s += c;
    }
    __shared__ int sm[1024];
    int mine = s; sm[t] = s; __syncthreads();
    for (int o = 1; o < 1024; o <<= 1) {
        int a = (t >= o) ? sm[t - o] : 0;
        __syncthreads(); sm[t] += a; __syncthreads();
    }
    int pre = sm[t] - mine;
#pragma unroll
    for (int j = 0; j < SC_T; ++j) {
        int idx = t * SC_T + j;
        if (idx < nsc) off_ch[idx] = pre + loc[j];
    }
}

__global__ __launch_bounds__(512) void scan_cur(int* __restrict__ cnt,
                                                const int* __restrict__ off_ch,
                                                int nsc) {
    int c = blockIdx.x * 512 + threadIdx.x;
    if (c >= nsc) return;
    int run = off_ch[c];
    for (int lb = 0; lb < NBLK; ++lb) {
        int v = cnt[(size_t)lb * CROW + c];
        cnt[(size_t)lb * CROW + c] = run;
        run += v;
    }
}

// ---------------------------------------------------------------------------
// Pass 3: placement, zero global atomics (LDS cursor row per block).
// pay = { local(5b)<<17 | src(17b), v (f32) }.
// ---------------------------------------------------------------------------
__global__ __launch_bounds__(512) void cplace_kernel(const int* __restrict__ keys,
                                                     const int* __restrict__ srcs,
                                                     const float* __restrict__ vals,
                                                     const int* __restrict__ cur_g,
                                                     int nsc,
                                                     uint2* __restrict__ pay) {
    __shared__ int cur[CROW];
    int lb = ((blockIdx.x & 7) << 5) | (blockIdx.x >> 3);
    const int* row = cur_g + (size_t)lb * CROW;
    for (int i = threadIdx.x; i < nsc; i += 512) cur[i] = row[i];
    __syncthreads();
    int base = lb * EPB;
    int b = lb >> 6;                     // behavior: 64 blocks per behavior
    for (int i = threadIdx.x; i < EPB; i += 512) {
        int gi = base + i;
        int k = keys[gi];
        float v = vals[gi];
        int src = srcs[gi];
        int pos = atomicAdd(&cur[k >> 3], 1);
        pay[pos] = make_uint2(((unsigned)(((k & 7) << 2) | b) << 17) | (unsigned)src,
                              __float_as_uint(v));
    }
}

// ---------------------------------------------------------------------------
// Pass 4 (fused): LDS counting-sort -> register accumulate (VECTOR
// addressing — round-8's readfirstlane chain serialized the gathers; keep
// per-lane addr calc so the compiler pipelines loads) -> d-major xs ->
// transform + sigmoid + wave-local behavior mean. ~25 KB LDS, 4 blocks/CU.
// ---------------------------------------------------------------------------
__global__ __launch_bounds__(512) void fused_kernel(
        const unsigned short* __restrict__ emb16,
        const float* __restrict__ W,
        const int* __restrict__ off_ch,
        const int* __restrict__ cnt_ch,
        const uint2* __restrict__ pay,
        float* __restrict__ embs,        // [B][nrows][64] <- sigmoid(x@W)
        float* __restrict__ mean_out,    // [nrows][64]    <- sigmoid(mean@W)
        int nrows) {
    int g = blockIdx.x;
    int start = off_ch[g], n = cnt_ch[g];
    int t = threadIdx.x, w = t >> 6, lane = t & 63;

    __shared__ uint2 st[CAP];            // staging; reused as xs after sort
    __shared__ uint2 st2[CAP];           // sorted payload
    __shared__ int c32[32];
    __shared__ int bstart[33];
    float* xs = (float*)st;              // [64][XSTR] d-major accumulators

    if (n <= CAP) {
        if (t < 32) c32[t] = 0;
        __syncthreads();
        for (int i = t; i < n; i += 512) {
            uint2 p = pay[start + i];
            st[i] = p;
            atomicAdd(&c32[p.x >> 17], 1);
        }
        __syncthreads();
        if (t == 0) {
            int s = 0;
            for (int b2 = 0; b2 < 32; ++b2) {
                bstart[b2] = s; s += c32[b2]; c32[b2] = bstart[b2];
            }
            bstart[32] = s;
        }
        __syncthreads();
        for (int i = t; i < n; i += 512) {
            uint2 p = st[i];
            int pos = atomicAdd(&c32[p.x >> 17], 1);
            st2[pos] = p;
        }
        __syncthreads();
        // Register accumulation, per-lane (vector) addressing, 2-wide ILP.
        float acc[4];
#pragma unroll
        for (int q = 0; q < 4; ++q) {
            int s0 = bstart[w * 4 + q], s1 = bstart[w * 4 + q + 1];
            float a0 = 0.f, a1 = 0.f;
            int j = s0;
#pragma unroll 2
            for (; j + 1 < s1; j += 2) {
                uint2 p0 = st2[j];
                uint2 p1 = st2[j + 1];
                float x0 = bf16x(emb16 + (size_t)(p0.x & 0x1FFFFu) * 64 + lane);
                float x1 = bf16x(emb16 + (size_t)(p1.x & 0x1FFFFu) * 64 + lane);
                a0 = fmaf(__uint_as_float(p0.y), x0, a0);
                a1 = fmaf(__uint_as_float(p1.y), x1, a1);
            }
            if (j < s1) {
                uint2 p0 = st2[j];
                float x0 = bf16x(emb16 + (size_t)(p0.x & 0x1FFFFu) * 64 + lane);
                a0 = fmaf(__uint_as_float(p0.y), x0, a0);
            }
            acc[q] = a0 + a1;
        }
        // st is dead (sort copied to st2); alias as xs. Intra-wave dep only.
        *(float4*)&xs[lane * XSTR + w * 4] =
            make_float4(acc[0], acc[1], acc[2], acc[3]);
    } else {
        // fallback (never for this input): unsorted LDS-atomic accumulate
        for (int i = t; i < 64 * XSTR; i += 512) xs[i] = 0.f;
        __syncthreads();
        for (int j = w; j < n; j += 8) {
            uint2 pv = pay[start + j];
            float x = bf16x(emb16 + (size_t)(pv.x & 0x1FFFFu) * 64 + lane);
            atomicAdd(&xs[lane * XSTR + (int)(pv.x >> 17)],
                      __uint_as_float(pv.y) * x);
        }
        __syncthreads();                 // cross-wave xs
    }

    // Transform: y[q][lane] = sum_d xs[d][w*4+q] * W[d][lane].
    // One broadcast ds_read_b128 per d serves all 4 bins.
    float y[4] = {0.f, 0.f, 0.f, 0.f};
#pragma unroll 4
    for (int d = 0; d < 64; ++d) {
        float4 xq = *(const float4*)&xs[d * XSTR + w * 4];
        float wv = W[d * 64 + lane];
        y[0] = fmaf(xq.x, wv, y[0]);
        y[1] = fmaf(xq.y, wv, y[1]);
        y[2] = fmaf(xq.z, wv, y[2]);
        y[3] = fmaf(xq.w, wv, y[3]);
    }
    int row = g * 8 + w;
#pragma unroll
    for (int q = 0; q < 4; ++q)
        embs[((long long)q * nrows + row) * 64 + lane] =
            1.f / (1.f + __expf(-y[q]));
    float m = 0.25f * (y[0] + y[1] + y[2] + y[3]);
    mean_out[(long long)row * 64 + lane] = 1.f / (1.f + __expf(-m));
}

// ---------------------------------------------------------------------------
// Deep fallback: atomic scatter + separate transform (only if ws too small).
// ---------------------------------------------------------------------------
__global__ void scatter_atomic_kernel(const float* __restrict__ user_emb,
                                      const float* __restrict__ item_emb,
                                      const int* __restrict__ rows,
                                      const int* __restrict__ cols,
                                      const float* __restrict__ vals,
                                      float* __restrict__ stack_u,
                                      float* __restrict__ stack_i) {
    long long tid = (long long)blockIdx.x * blockDim.x + threadIdx.x;
    long long e  = tid >> 4;
    int lane = (int)(tid & 15);
    if (e >= (long long)EDGES) return;
    int b = (int)(e / E_N);
    int r = rows[e];
    int c = cols[e];
    float v = vals[e];
    const float4* irow = (const float4*)(item_emb + (long long)c * D_N);
    const float4* urow = (const float4*)(user_emb + (long long)r * D_N);
    float4 iv = irow[lane];
    float4 uv = urow[lane];
    float* du = stack_u + ((long long)b * U_N + r) * D_N + lane * 4;
    float* di = stack_i + ((long long)b * I_N + c) * D_N + lane * 4;
    atomicAdd(du + 0, v * iv.x);
    atomicAdd(du + 1, v * iv.y);
    atomicAdd(du + 2, v * iv.z);
    atomicAdd(du + 3, v * iv.w);
    atomicAdd(di + 0, v * uv.x);
    atomicAdd(di + 1, v * uv.y);
    atomicAdd(di + 2, v * uv.z);
    atomicAdd(di + 3, v * uv.w);
}

template <int NROWS>
__global__ __launch_bounds__(64) void transform_kernel(
        float* __restrict__ stack,
        const float* __restrict__ W,
        float* __restrict__ mean_out) {
    const int row = blockIdx.x;
    const int j   = threadIdx.x;
    __shared__ float xs[B_N][D_N];
#pragma unroll
    for (int b = 0; b < B_N; ++b)
        xs[b][j] = stack[((long long)b * NROWS + row) * D_N + j];
    __syncthreads();
    float acc[B_N] = {0.f, 0.f, 0.f, 0.f};
#pragma unroll 8
    for (int d = 0; d < D_N; ++d) {
        float w = W[d * D_N + j];
#pragma unroll
        for (int b = 0; b < B_N; ++b)
            acc[b] += xs[b][d] * w;
    }
    float m = 0.25f * (acc[0] + acc[1] + acc[2] + acc[3]);
#pragma unroll
    for (int b = 0; b < B_N; ++b)
        stack[((long long)b * NROWS + row) * D_N + j] =
            1.0f / (1.0f + __expf(-acc[b]));
    mean_out[(long long)row * D_N + j] = 1.0f / (1.0f + __expf(-m));
}

// ---------------------------------------------------------------------------
extern "C" void kernel_launch(void* const* d_in, const int* in_sizes, int n_in,
                              void* d_out, int out_size, void* d_ws, size_t ws_size,
                              hipStream_t stream) {
    const float* user_emb = (const float*)d_in[0];
    const float* item_emb = (const float*)d_in[1];
    const int*   rows     = (const int*)  d_in[2];
    const int*   cols     = (const int*)  d_in[3];
    const float* vals     = (const float*)d_in[4];
    const float* u_w      = (const float*)d_in[5];
    const float* i_w      = (const float*)d_in[6];

    float* out = (float*)d_out;
    float* user_mean = out;
    float* item_mean = out + (long long)U_N * D_N;
    float* stack_u   = item_mean + (long long)I_N * D_N;     // user_embs out
    float* stack_i   = stack_u + (long long)B_N * U_N * D_N; // item_embs out

    // Workspace: cnt [NBLK][CROW] | cnt_ch | off_ch | pay [EDGES] | bf16 tables
    int* cnt    = (int*)d_ws;
    int* cnt_ch = cnt + (size_t)NBLK * CROW;
    int* off_ch = cnt_ch + CROW;
    uint2* pay  = (uint2*)(off_ch + CROW);
    unsigned short* user16 = (unsigned short*)(pay + EDGES);
    unsigned short* item16 = user16 + (size_t)U_N * D_N;
    size_t needed = ((size_t)NBLK * CROW + 2 * CROW) * 4 +
                    (size_t)EDGES * 8 + (size_t)(U_N + I_N) * D_N * 2; // ~96 MB

    if (ws_size >= needed) {
        int ncvt = (U_N + I_N) * D_N;
        cvt_kernel<<<(ncvt + 255) / 256, 256, 0, stream>>>(user_emb, item_emb,
                                                           user16, item16);
        // ---- user side: keys=rows, gathers item table ----
        bhist_kernel<<<NBLK, 512, 0, stream>>>(rows, NSC_U, cnt);
        scan_tot<<<(NSC_U + 511) / 512, 512, 0, stream>>>(cnt, NSC_U, cnt_ch);
        scan_ex<<<1, 1024, 0, stream>>>(cnt_ch, NSC_U, off_ch);
        scan_cur<<<(NSC_U + 511) / 512, 512, 0, stream>>>(cnt, off_ch, NSC_U);
        cplace_kernel<<<NBLK, 512, 0, stream>>>(rows, cols, vals, cnt, NSC_U, pay);
        fused_kernel<<<NSC_U, 512, 0, stream>>>(item16, u_w, off_ch, cnt_ch, pay,
                                                stack_u, user_mean, U_N);
        // ---- item side: keys=cols, gathers user table ----
        bhist_kernel<<<NBLK, 512, 0, stream>>>(cols, NSC_I, cnt);
        scan_tot<<<(NSC_I + 511) / 512, 512, 0, stream>>>(cnt, NSC_I, cnt_ch);
        scan_ex<<<1, 1024, 0, stream>>>(cnt_ch, NSC_I, off_ch);
        scan_cur<<<(NSC_I + 511) / 512, 512, 0, stream>>>(cnt, off_ch, NSC_I);
        cplace_kernel<<<NBLK, 512, 0, stream>>>(cols, rows, vals, cnt, NSC_I, pay);
        fused_kernel<<<NSC_I, 512, 0, stream>>>(user16, i_w, off_ch, cnt_ch, pay,
                                                stack_i, item_mean, I_N);
    } else {
        size_t stack_bytes = sizeof(float) * (size_t)B_N * (U_N + I_N) * D_N;
        hipMemsetAsync(stack_u, 0, stack_bytes, stream);
        long long nthreads = (long long)EDGES * 16;
        int nblocks = (int)((nthreads + 255) / 256);
        scatter_atomic_kernel<<<nblocks, 256, 0, stream>>>(
            user_emb, item_emb, rows, cols, vals, stack_u, stack_i);
        transform_kernel<U_N><<<U_N, 64, 0, stream>>>(stack_u, u_w, user_mean);
        transform_kernel<I_N><<<I_N, 64, 0, stream>>>(stack_i, i_w, item_mean);
    }
}

// Round 10
// 906.692 us; speedup vs baseline: 1.5534x; 1.0315x over previous
//
#include <hip/hip_runtime.h>

#define U_N 100000
#define I_N 50000
#define D_N 64
#define B_N 4
#define E_N 2000000

#define EDGES   (B_N * E_N)            // 8,000,000 edge-entries per side
#define NSC_U   (U_N / 8)              // 12,500 chunks (8 rows x 4 behaviors)
#define NSC_I   (I_N / 8)              // 6,250 item chunks
#define CROW    12544                  // padded chunk-row length (>= NSC_U)
#define NBLK    256                    // partition blocks (32 per XCD)
#define EPB     (EDGES / NBLK)         // 31,250 entries per block (exact)
#define CAP     1536                   // fused-kernel LDS sort capacity
#define XSTR    36                     // xs leading stride (dwords), pad vs 32
#define SC_T    13                     // 1024*13 >= 12,500

// Bin key: bin = row*4 + behavior -> chunk = row>>3, local = ((row&7)<<2)|b.
// User side: keys=rows, gathers item table. Item side: keys=cols, gathers user.

// ---------------------------------------------------------------------------
// Pass 0: convert both embedding tables to bf16 (RNE).
// ---------------------------------------------------------------------------
__global__ __launch_bounds__(256) void cvt_kernel(const float* __restrict__ ue,
                                                  const float* __restrict__ ie,
                                                  unsigned short* __restrict__ u16,
                                                  unsigned short* __restrict__ i16) {
    int i = blockIdx.x * 256 + threadIdx.x;
    int nu = U_N * D_N;
    int ni = I_N * D_N;
    if (i < nu) {
        unsigned u = __float_as_uint(ue[i]);
        u += 0x7FFFu + ((u >> 16) & 1u);
        u16[i] = (unsigned short)(u >> 16);
    } else if (i < nu + ni) {
        int j = i - nu;
        unsigned u = __float_as_uint(ie[j]);
        u += 0x7FFFu + ((u >> 16) & 1u);
        i16[j] = (unsigned short)(u >> 16);
    }
}

// ---------------------------------------------------------------------------
// Pass 1: per-(block, chunk) histogram; block lb owns entries [lb*EPB, ...).
// ---------------------------------------------------------------------------
__global__ __launch_bounds__(512) void bhist_kernel(const int* __restrict__ keys,
                                                    int nsc,
                                                    int* __restrict__ cnt) {
    __shared__ int h[CROW];
    for (int i = threadIdx.x; i < nsc; i += 512) h[i] = 0;
    __syncthreads();
    int lb = ((blockIdx.x & 7) << 5) | (blockIdx.x >> 3);
    int base = lb * EPB;
    for (int i = threadIdx.x; i < EPB; i += 512)
        atomicAdd(&h[keys[base + i] >> 3], 1);
    __syncthreads();
    int* row = cnt + (size_t)lb * CROW;
    for (int i = threadIdx.x; i < nsc; i += 512) row[i] = h[i];
}

// ---------------------------------------------------------------------------
// Pass 2: totals, exclusive scan, then counts -> per-block cursors in place.
// ---------------------------------------------------------------------------
__global__ __launch_bounds__(512) void scan_tot(const int* __restrict__ cnt,
                                                int nsc, int* __restrict__ cnt_ch) {
    int c = blockIdx.x * 512 + threadIdx.x;
    if (c >= nsc) return;
    int s = 0;
    for (int lb = 0; lb < NBLK; ++lb) s += cnt[(size_t)lb * CROW + c];
    cnt_ch[c] = s;
}

__global__ __launch_bounds__(1024) void scan_ex(const int* __restrict__ cnt_ch,
                                                int nsc, int* __restrict__ off_ch) {
    int t = threadIdx.x;
    int loc[SC_T]; int s = 0;
#pragma unroll
    for (int j = 0; j < SC_T; ++j) {
        int idx = t * SC_T + j;
        int c = (idx < nsc) ? cnt_ch[idx] : 0;
        loc[j] = s; s += c;
    }
    __shared__ int sm[1024];
    int mine = s; sm[t] = s; __syncthreads();
    for (int o = 1; o < 1024; o <<= 1) {
        int a = (t >= o) ? sm[t - o] : 0;
        __syncthreads(); sm[t] += a; __syncthreads();
    }
    int pre = sm[t] - mine;
#pragma unroll
    for (int j = 0; j < SC_T; ++j) {
        int idx = t * SC_T + j;
        if (idx < nsc) off_ch[idx] = pre + loc[j];
    }
}

__global__ __launch_bounds__(512) void scan_cur(int* __restrict__ cnt,
                                                const int* __restrict__ off_ch,
                                                int nsc) {
    int c = blockIdx.x * 512 + threadIdx.x;
    if (c >= nsc) return;
    int run = off_ch[c];
    for (int lb = 0; lb < NBLK; ++lb) {
        int v = cnt[(size_t)lb * CROW + c];
        cnt[(size_t)lb * CROW + c] = run;
        run += v;
    }
}

// ---------------------------------------------------------------------------
// Pass 3: placement, zero global atomics (LDS cursor row per block).
// pay = { local(5b)<<17 | src(17b), v (f32) }.
// ---------------------------------------------------------------------------
__global__ __launch_bounds__(512) void cplace_kernel(const int* __restrict__ keys,
                                                     const int* __restrict__ srcs,
                                                     const float* __restrict__ vals,
                                                     const int* __restrict__ cur_g,
                                                     int nsc,
                                                     uint2* __restrict__ pay) {
    __shared__ int cur[CROW];
    int lb = ((blockIdx.x & 7) << 5) | (blockIdx.x >> 3);
    const int* row = cur_g + (size_t)lb * CROW;
    for (int i = threadIdx.x; i < nsc; i += 512) cur[i] = row[i];
    __syncthreads();
    int base = lb * EPB;
    int b = lb >> 6;                     // behavior: 64 blocks per behavior
    for (int i = threadIdx.x; i < EPB; i += 512) {
        int gi = base + i;
        int k = keys[gi];
        float v = vals[gi];
        int src = srcs[gi];
        int pos = atomicAdd(&cur[k >> 3], 1);
        pay[pos] = make_uint2(((unsigned)(((k & 7) << 2) | b) << 17) | (unsigned)src,
                              __float_as_uint(v));
    }
}

// ---------------------------------------------------------------------------
// Pass 4 (fused): LDS counting-sort -> quad-row register accumulate (wave
// split into 4 quarters; one dwordx2 load covers 4 rows/wave; shfl_xor
// reduce across quarters) -> d-major xs -> transform + sigmoid + mean.
// ~25 KB LDS, 4 blocks/CU.
// ---------------------------------------------------------------------------
__global__ __launch_bounds__(512) void fused_kernel(
        const unsigned short* __restrict__ emb16,
        const float* __restrict__ W,
        const int* __restrict__ off_ch,
        const int* __restrict__ cnt_ch,
        const uint2* __restrict__ pay,
        float* __restrict__ embs,        // [B][nrows][64] <- sigmoid(x@W)
        float* __restrict__ mean_out,    // [nrows][64]    <- sigmoid(mean@W)
        int nrows) {
    int g = blockIdx.x;
    int start = off_ch[g], n = cnt_ch[g];
    int t = threadIdx.x, w = t >> 6, lane = t & 63;

    __shared__ uint2 st[CAP];            // staging; reused as xs after sort
    __shared__ uint2 st2[CAP];           // sorted payload
    __shared__ int c32[32];
    __shared__ int bstart[33];
    float* xs = (float*)st;              // [64][XSTR] d-major accumulators

    if (n <= CAP) {
        if (t < 32) c32[t] = 0;
        __syncthreads();
        for (int i = t; i < n; i += 512) {
            uint2 p = pay[start + i];
            st[i] = p;
            atomicAdd(&c32[p.x >> 17], 1);
        }
        __syncthreads();
        if (t == 0) {
            int s = 0;
            for (int b2 = 0; b2 < 32; ++b2) {
                bstart[b2] = s; s += c32[b2]; c32[b2] = bstart[b2];
            }
            bstart[32] = s;
        }
        __syncthreads();
        for (int i = t; i < n; i += 512) {
            uint2 p = st[i];
            int pos = atomicAdd(&c32[p.x >> 17], 1);
            st2[pos] = p;
        }
        __syncthreads();

        // Quad-row accumulate: quarter qt handles entry j+qt; lane covers
        // dims 4*ql..4*ql+3 of that entry's row via one dwordx2 load.
        int qt = lane >> 4, ql = lane & 15;
        float4 a0, a1, a2, a3;
#define ACC_BIN(AQ, Q)                                                        \
        {                                                                     \
            int s0 = bstart[w * 4 + (Q)], s1 = bstart[w * 4 + (Q) + 1];       \
            AQ = make_float4(0.f, 0.f, 0.f, 0.f);                             \
            for (int j = s0; j < s1; j += 4) {                                \
                int idx = j + qt;                                             \
                int jj = idx < s1 ? idx : s1 - 1;                             \
                uint2 p = st2[jj];                                            \
                float v = (idx < s1) ? __uint_as_float(p.y) : 0.f;            \
                uint2 x = *((const uint2*)(emb16 +                            \
                              (size_t)(p.x & 0x1FFFFu) * 64) + ql);           \
                AQ.x = fmaf(v, __uint_as_float(x.x << 16), AQ.x);             \
                AQ.y = fmaf(v, __uint_as_float(x.x & 0xFFFF0000u), AQ.y);     \
                AQ.z = fmaf(v, __uint_as_float(x.y << 16), AQ.z);             \
                AQ.w = fmaf(v, __uint_as_float(x.y & 0xFFFF0000u), AQ.w);     \
            }                                                                 \
            AQ.x += __shfl_xor(AQ.x, 16); AQ.x += __shfl_xor(AQ.x, 32);       \
            AQ.y += __shfl_xor(AQ.y, 16); AQ.y += __shfl_xor(AQ.y, 32);       \
            AQ.z += __shfl_xor(AQ.z, 16); AQ.z += __shfl_xor(AQ.z, 32);       \
            AQ.w += __shfl_xor(AQ.w, 16); AQ.w += __shfl_xor(AQ.w, 32);       \
        }
        ACC_BIN(a0, 0)
        ACC_BIN(a1, 1)
        ACC_BIN(a2, 2)
        ACC_BIN(a3, 3)
#undef ACC_BIN
        // st dead after sort copy; alias as xs. Wave w writes columns
        // w*4..w*4+3 for all dims (intra-wave dep with the transform reads).
        if (qt == 0) {
            *(float4*)&xs[(4 * ql + 0) * XSTR + w * 4] =
                make_float4(a0.x, a1.x, a2.x, a3.x);
            *(float4*)&xs[(4 * ql + 1) * XSTR + w * 4] =
                make_float4(a0.y, a1.y, a2.y, a3.y);
            *(float4*)&xs[(4 * ql + 2) * XSTR + w * 4] =
                make_float4(a0.z, a1.z, a2.z, a3.z);
            *(float4*)&xs[(4 * ql + 3) * XSTR + w * 4] =
                make_float4(a0.w, a1.w, a2.w, a3.w);
        }
    } else {
        // fallback (never for this input): unsorted LDS-atomic accumulate
        for (int i = t; i < 64 * XSTR; i += 512) xs[i] = 0.f;
        __syncthreads();
        for (int j = w; j < n; j += 8) {
            uint2 pv = pay[start + j];
            float x = __uint_as_float(
                (unsigned)emb16[(size_t)(pv.x & 0x1FFFFu) * 64 + lane] << 16);
            atomicAdd(&xs[lane * XSTR + (int)(pv.x >> 17)],
                      __uint_as_float(pv.y) * x);
        }
        __syncthreads();                 // cross-wave xs
    }

    // Transform: y[q][lane] = sum_d xs[d][w*4+q] * W[d][lane].
    // One broadcast ds_read_b128 per d serves all 4 bins.
    float y[4] = {0.f, 0.f, 0.f, 0.f};
#pragma unroll 4
    for (int d = 0; d < 64; ++d) {
        float4 xq = *(const float4*)&xs[d * XSTR + w * 4];
        float wv = W[d * 64 + lane];
        y[0] = fmaf(xq.x, wv, y[0]);
        y[1] = fmaf(xq.y, wv, y[1]);
        y[2] = fmaf(xq.z, wv, y[2]);
        y[3] = fmaf(xq.w, wv, y[3]);
    }
    int row = g * 8 + w;
#pragma unroll
    for (int q = 0; q < 4; ++q)
        embs[((long long)q * nrows + row) * 64 + lane] =
            1.f / (1.f + __expf(-y[q]));
    float m = 0.25f * (y[0] + y[1] + y[2] + y[3]);
    mean_out[(long long)row * 64 + lane] = 1.f / (1.f + __expf(-m));
}

// ---------------------------------------------------------------------------
// Deep fallback: atomic scatter + separate transform (only if ws too small).
// ---------------------------------------------------------------------------
__global__ void scatter_atomic_kernel(const float* __restrict__ user_emb,
                                      const float* __restrict__ item_emb,
                                      const int* __restrict__ rows,
                                      const int* __restrict__ cols,
                                      const float* __restrict__ vals,
                                      float* __restrict__ stack_u,
                                      float* __restrict__ stack_i) {
    long long tid = (long long)blockIdx.x * blockDim.x + threadIdx.x;
    long long e  = tid >> 4;
    int lane = (int)(tid & 15);
    if (e >= (long long)EDGES) return;
    int b = (int)(e / E_N);
    int r = rows[e];
    int c = cols[e];
    float v = vals[e];
    const float4* irow = (const float4*)(item_emb + (long long)c * D_N);
    const float4* urow = (const float4*)(user_emb + (long long)r * D_N);
    float4 iv = irow[lane];
    float4 uv = urow[lane];
    float* du = stack_u + ((long long)b * U_N + r) * D_N + lane * 4;
    float* di = stack_i + ((long long)b * I_N + c) * D_N + lane * 4;
    atomicAdd(du + 0, v * iv.x);
    atomicAdd(du + 1, v * iv.y);
    atomicAdd(du + 2, v * iv.z);
    atomicAdd(du + 3, v * iv.w);
    atomicAdd(di + 0, v * uv.x);
    atomicAdd(di + 1, v * uv.y);
    atomicAdd(di + 2, v * uv.z);
    atomicAdd(di + 3, v * uv.w);
}

template <int NROWS>
__global__ __launch_bounds__(64) void transform_kernel(
        float* __restrict__ stack,
        const float* __restrict__ W,
        float* __restrict__ mean_out) {
    const int row = blockIdx.x;
    const int j   = threadIdx.x;
    __shared__ float xs[B_N][D_N];
#pragma unroll
    for (int b = 0; b < B_N; ++b)
        xs[b][j] = stack[((long long)b * NROWS + row) * D_N + j];
    __syncthreads();
    float acc[B_N] = {0.f, 0.f, 0.f, 0.f};
#pragma unroll 8
    for (int d = 0; d < D_N; ++d) {
        float w = W[d * D_N + j];
#pragma unroll
        for (int b = 0; b < B_N; ++b)
            acc[b] += xs[b][d] * w;
    }
    float m = 0.25f * (acc[0] + acc[1] + acc[2] + acc[3]);
#pragma unroll
    for (int b = 0; b < B_N; ++b)
        stack[((long long)b * NROWS + row) * D_N + j] =
            1.0f / (1.0f + __expf(-acc[b]));
    mean_out[(long long)row * D_N + j] = 1.0f / (1.0f + __expf(-m));
}

// ---------------------------------------------------------------------------
extern "C" void kernel_launch(void* const* d_in, const int* in_sizes, int n_in,
                              void* d_out, int out_size, void* d_ws, size_t ws_size,
                              hipStream_t stream) {
    const float* user_emb = (const float*)d_in[0];
    const float* item_emb = (const float*)d_in[1];
    const int*   rows     = (const int*)  d_in[2];
    const int*   cols     = (const int*)  d_in[3];
    const float* vals     = (const float*)d_in[4];
    const float* u_w      = (const float*)d_in[5];
    const float* i_w      = (const float*)d_in[6];

    float* out = (float*)d_out;
    float* user_mean = out;
    float* item_mean = out + (long long)U_N * D_N;
    float* stack_u   = item_mean + (long long)I_N * D_N;     // user_embs out
    float* stack_i   = stack_u + (long long)B_N * U_N * D_N; // item_embs out

    // Workspace: cnt [NBLK][CROW] | cnt_ch | off_ch | pay [EDGES] | bf16 tables
    int* cnt    = (int*)d_ws;
    int* cnt_ch = cnt + (size_t)NBLK * CROW;
    int* off_ch = cnt_ch + CROW;
    uint2* pay  = (uint2*)(off_ch + CROW);
    unsigned short* user16 = (unsigned short*)(pay + EDGES);
    unsigned short* item16 = user16 + (size_t)U_N * D_N;
    size_t needed = ((size_t)NBLK * CROW + 2 * CROW) * 4 +
                    (size_t)EDGES * 8 + (size_t)(U_N + I_N) * D_N * 2; // ~96 MB

    if (ws_size >= needed) {
        int ncvt = (U_N + I_N) * D_N;
        cvt_kernel<<<(ncvt + 255) / 256, 256, 0, stream>>>(user_emb, item_emb,
                                                           user16, item16);
        // ---- user side: keys=rows, gathers item table ----
        bhist_kernel<<<NBLK, 512, 0, stream>>>(rows, NSC_U, cnt);
        scan_tot<<<(NSC_U + 511) / 512, 512, 0, stream>>>(cnt, NSC_U, cnt_ch);
        scan_ex<<<1, 1024, 0, stream>>>(cnt_ch, NSC_U, off_ch);
        scan_cur<<<(NSC_U + 511) / 512, 512, 0, stream>>>(cnt, off_ch, NSC_U);
        cplace_kernel<<<NBLK, 512, 0, stream>>>(rows, cols, vals, cnt, NSC_U, pay);
        fused_kernel<<<NSC_U, 512, 0, stream>>>(item16, u_w, off_ch, cnt_ch, pay,
                                                stack_u, user_mean, U_N);
        // ---- item side: keys=cols, gathers user table ----
        bhist_kernel<<<NBLK, 512, 0, stream>>>(cols, NSC_I, cnt);
        scan_tot<<<(NSC_I + 511) / 512, 512, 0, stream>>>(cnt, NSC_I, cnt_ch);
        scan_ex<<<1, 1024, 0, stream>>>(cnt_ch, NSC_I, off_ch);
        scan_cur<<<(NSC_I + 511) / 512, 512, 0, stream>>>(cnt, off_ch, NSC_I);
        cplace_kernel<<<NBLK, 512, 0, stream>>>(cols, rows, vals, cnt, NSC_I, pay);
        fused_kernel<<<NSC_I, 512, 0, stream>>>(user16, i_w, off_ch, cnt_ch, pay,
                                                stack_i, item_mean, I_N);
    } else {
        size_t stack_bytes = sizeof(float) * (size_t)B_N * (U_N + I_N) * D_N;
        hipMemsetAsync(stack_u, 0, stack_bytes, stream);
        long long nthreads = (long long)EDGES * 16;
        int nblocks = (int)((nthreads + 255) / 256);
        scatter_atomic_kernel<<<nblocks, 256, 0, stream>>>(
            user_emb, item_emb, rows, cols, vals, stack_u, stack_i);
        transform_kernel<U_N><<<U_N, 64, 0, stream>>>(stack_u, u_w, user_mean);
        transform_kernel<I_N><<<I_N, 64, 0, stream>>>(stack_i, i_w, item_mean);
    }
}